// Round 4
// baseline (160.657 us; speedup 1.0000x reference)
//
#include <hip/hip_runtime.h>

#define DIM 32
#define NB  6
#define INV2PI 0.15915494309189535f

typedef __attribute__((ext_vector_type(8)))  _Float16 half8;
typedef __attribute__((ext_vector_type(16))) float floatx16;

union H8I4 { half8 h; int i[4]; };

// RNE f32x2 -> packed f16x2 (prologue only, cost irrelevant)
__device__ __forceinline__ int pkrne(float a, float b) {
    _Float16 h0 = (_Float16)a, h1 = (_Float16)b;
    unsigned short u0, u1;
    __builtin_memcpy(&u0, &h0, 2); __builtin_memcpy(&u1, &h1, 2);
    return (int)(u0 | ((unsigned)u1 << 16));
}
// RTZ f32x2 -> packed f16x2, single v_cvt_pkrtz_f16_f32 (hot path)
#if __has_builtin(__builtin_amdgcn_cvt_pkrtz)
__device__ __forceinline__ int pkrtz(float a, float b) {
    auto h = __builtin_amdgcn_cvt_pkrtz(a, b);
    int r; __builtin_memcpy(&r, &h, 4); return r;
}
#else
#define pkrtz pkrne
#endif

// B-frag slot (s,h,j) holds raw channel P; C/D reg (r,h) holds raw channel Q.
__device__ __forceinline__ int Pmap(int s, int h, int j) { return 16*s + 8*(j>>2) + 4*h + (j&3); }
__device__ __forceinline__ int Qmap(int p)               { int r = p & 15, h = p >> 4; return 8*(r>>2) + 4*h + (r&3); }

#define MFMA(a, b, c) __builtin_amdgcn_mfma_f32_32x32x16_f16((a), (b), (c), 0, 0, 0)

// acc in revolution domain (weights prescaled by 1/2pi): raw v_sin, then
// single-f16 activation pack via v_cvt_pkrtz (R2: measured 87us, absmax 9.8e-4).
__device__ __forceinline__ void sinsplit(const floatx16& acc, half8& b1, half8& b2) {
    H8I4 n1, n2;
    #pragma unroll
    for (int q = 0; q < 4; ++q) {
        n1.i[q] = pkrtz(__builtin_amdgcn_sinf(acc[2*q]),
                        __builtin_amdgcn_sinf(acc[2*q+1]));
        n2.i[q] = pkrtz(__builtin_amdgcn_sinf(acc[8+2*q]),
                        __builtin_amdgcn_sinf(acc[8+2*q+1]));
    }
    b1 = n1.h; b2 = n2.h;
}

// LDS: 544 floats (2176 B) + (16384+1536+256) shorts (36352 B) = 38528 B
// -> 4 blocks/CU (154,112 <= 163,840).
#define LDS_BYTES 38528

// NOTE (measured R4/R5 prev session): __launch_bounds__ arg2 = min BLOCKS/CU
// on this toolchain. (512,4) -> 64-VGPR cap.
// Spill tripwire: hbm_bytes (clean ~5 MB; spilled R1 was 2.3 GB at VGPR=64).
// R1 lesson: sched_barrier(0) fences are LOAD-HOISTING FENCES — removing
// them entirely lets unrolled loops hoist ds_reads en masse past the
// 64-VGPR cap -> scratch spill -> 7x regression. DO NOT REMOVE.
// R4 refinement: fences moved INSIDE each layer so that sinsplit(l) shares a
// scheduling region with the data-independent next-layer work (cf/ia loads +
// inject MFMA in f; cg/wz loads + wz MFMAs in g). Per-region load count is
// still bounded at 7-8 b128 -> no hoist blowup.
__global__ __launch_bounds__(512, 4) void sep_mfma(
    const float* __restrict__ coords,
    const float* __restrict__ x_params,
    const float* __restrict__ t_params,
    const float* __restrict__ xW1, const float* __restrict__ xb1,
    const float* __restrict__ xW2, const float* __restrict__ xb2,
    const float* __restrict__ tW1, const float* __restrict__ tb1,
    const float* __restrict__ tW2, const float* __restrict__ tb2,
    const float* __restrict__ h0,  const float* __restrict__ gh0,
    const float* __restrict__ f_Wh, const float* __restrict__ f_bh,
    const float* __restrict__ f_Wz, const float* __restrict__ f_bz,
    const float* __restrict__ g_Wh, const float* __restrict__ g_bh,
    const float* __restrict__ g_Wz, const float* __restrict__ g_bz,
    const float* __restrict__ d_W,  const float* __restrict__ d_b,
    float* __restrict__ out)
{
    extern __shared__ char smem[];
    float* sCgp   = (float*)smem;            // [6][32] Cg/2pi (permuted, +gh0 fold at l=0)
    float* rawCfP = sCgp + 192;              // [6][32] Cf/2pi (permuted, +h0 fold at l=0)
    float* sdWp   = rawCfP + 192;            // [32] d_W (permuted, NOT scaled)
    float* shx    = sdWp + 32;
    float* sht    = shx + 32;
    float* sex    = sht + 32;
    float* set_   = sex + 32;
    // image: [f_Wh l=1..5 | g_Wh l=1..5 | g_Wz l=0..5] x [2 s-halves x 512], f16
    unsigned short* sImg  = (unsigned short*)(set_ + 32);  // 16 slots * 1024 shorts
    // R3: coordinate-inject A-frags: per f-layer 32 lanes x 8 f16
    // [z0h,z0h,z0l,z1h,z1h,z1l,0,0] (hi/lo split, prescaled by 1/2pi)
    unsigned short* sInj  = sImg + 16384;                  // 6 * 256 shorts
    unsigned short* sZero = sInj + 1536;                   // 256 shorts of zeros (hg=1 A half)

    const int tid = threadIdx.x;
    const int b   = blockIdx.x >> 6;          // 64 blocks per batch
    const int ig  = (blockIdx.x >> 1) & 31;   // i-group: 8 i's per block
    const int jg  = blockIdx.x & 1;           // j-half: 4 tiles per block

    // ================= PROLOGUE =================
    // P1: encoder stage 1 + A-frag image build (RNE f16, prescaled,
    // packed 2 channels per int store; l=0 of f_Wh/g_Wh folded -> omitted)
    if (tid < 32) {
        float a = xb1[tid];
        for (int k = 0; k < 16; ++k) a = fmaf(x_params[b * 16 + k], xW1[k * 32 + tid], a);
        shx[tid] = __sinf(a);
    } else if (tid < 64) {
        int d = tid - 32;
        float a = tb1[d];
        for (int k = 0; k < 8; ++k) a = fmaf(t_params[b * 8 + k], tW1[k * 32 + d], a);
        sht[d] = __sinf(a);
    }
    if (tid < 128) ((int*)sZero)[tid] = 0;
    {
        int* sImgI = (int*)sImg;
        for (int ii = tid; ii < 8192; ii += 512) {
            int region = ii >> 9;             // slot index 0..15 (block-uniform)
            int r = ii & 511;
            int s = r >> 8, t = r & 255;
            int lane = t >> 2, jj2 = t & 3;
            int m = lane & 31, hg = lane >> 5;
            int c0 = 16*s + 8*(jj2 >> 1) + 4*hg + 2*(jj2 & 1);  // Pmap(s,hg,2*jj2)
            float w0, w1;
            if (region < 5)       { int l = region + 1;  w0 = f_Wh[(l*32 + c0)*32 + m]; w1 = f_Wh[(l*32 + c0 + 1)*32 + m]; }
            else if (region < 10) { int l = region - 4;  w0 = g_Wh[(l*32 + c0)*32 + m]; w1 = g_Wh[(l*32 + c0 + 1)*32 + m]; }
            else                  { int l = region - 10; w0 = g_Wz[(l*64 + c0)*32 + m]; w1 = g_Wz[(l*64 + c0 + 1)*32 + m]; }
            sImgI[ii] = pkrne(w0 * INV2PI, w1 * INV2PI);
        }
    }
    __syncthreads();

    // P2: encoder stage 2 + inject A-frag build + dWp
    if (tid < 32) {
        float a = xb2[tid];
        for (int c = 0; c < 32; ++c) a = fmaf(shx[c], xW2[c * 32 + tid], a);
        sex[tid] = a;
    } else if (tid < 64) {
        int d = tid - 32;
        float a = tb2[d];
        for (int c = 0; c < 32; ++c) a = fmaf(sht[c], tW2[c * 32 + d], a);
        set_[d] = a;
    }
    if (tid < 192) {
        // inject frag for layer l, output row m: hi/lo split of z0,z1
        int l = tid >> 5, m = tid & 31;
        float z0 = f_Wz[(l * 34 + 0) * 32 + m] * INV2PI;
        float z1 = f_Wz[(l * 34 + 1) * 32 + m] * INV2PI;
        _Float16 h0_ = (_Float16)z0; float z0h = (float)h0_, z0l = z0 - z0h;
        _Float16 h1_ = (_Float16)z1; float z1h = (float)h1_, z1l = z1 - z1h;
        int* p = (int*)sInj + 4 * tid;
        p[0] = pkrne(z0h, z0h);
        p[1] = pkrne(z0l, z1h);
        p[2] = pkrne(z1h, z1l);
        p[3] = 0;
    }
    if (tid < 32) sdWp[tid] = d_W[Qmap(tid)];
    __syncthreads();

    // P3: Cf and Cg (permuted, prescaled; h0/gh0 matvecs folded into l=0)
    if (tid < 192) {
        int l = tid >> 5, p = tid & 31, d = Qmap(p);
        float a = f_bh[l * 32 + d] + f_bz[l * 32 + d];
        for (int c = 0; c < 32; ++c) a = fmaf(set_[c], f_Wz[(l * 34 + 2 + c) * 32 + d], a);
        if (l == 0)
            for (int c = 0; c < 32; ++c) a = fmaf(h0[c], f_Wh[c * 32 + d], a);
        rawCfP[tid] = a * INV2PI;
        float g = g_bh[l * 32 + d] + g_bz[l * 32 + d];
        for (int c = 0; c < 32; ++c) g = fmaf(sex[c], g_Wz[(l * 64 + 32 + c) * 32 + d], g);
        if (l == 0)
            for (int c = 0; c < 32; ++c) g = fmaf(gh0[c], g_Wh[c * 32 + d], g);
        sCgp[tid] = g * INV2PI;
    }
    __syncthreads();

    // ================= MAIN =================
    const int lane = tid & 63, wave = tid >> 6;
    const int i = ig * 8 + wave;
    const int e = lane & 31, hk = lane >> 5;
    const int pb = hk * 16;
    const float ti = coords[(b * 256 + i) * 2 + 1];
    const float db = d_b[0];

    // hi/lo split of ti (wave-uniform), hoisted out of the tile loop
    float th_, tl_;
    { _Float16 h = (_Float16)ti; th_ = (float)h; tl_ = ti - th_; }

    // inject A-frag base: hg=0 lanes walk sInj per layer; hg=1 lanes read the
    // shared zero block (their virtual channels are unused -> A rows exact 0,
    // which also makes hk=1 lanes' B content don't-care).
    const unsigned short* injbase = hk ? sZero : (sInj + e * 8);
    const int injstep = hk ? 0 : 256;   // shorts per layer

    #pragma unroll 1
    for (int t = 0; t < 4; ++t) {
        const int tile = jg * 4 + t;
        const int j = tile * 32 + e;
        const float xj = coords[(b * 256 + j) * 2];

        // B-frag [xh,xl,xh,th,tl,th,0,0]: compensated hi/lo split ->
        // inject MFMA reproduces xj*z0 + ti*z1 to ~2^-21 rel (no accuracy loss
        // vs the f32 FMA path it replaces).
        float xh_, xl_;
        { _Float16 h = (_Float16)xj; xh_ = (float)h; xl_ = xj - xh_; }
        H8I4 xtb;
        xtb.i[0] = pkrtz(xh_, xl_);
        xtb.i[1] = pkrtz(xh_, th_);
        xtb.i[2] = pkrtz(tl_, th_);
        xtb.i[3] = 0;
        const half8 xtB = xtb.h;

        floatx16 acc;
        half8 hB1, hB2;
        const unsigned short* ip = injbase;

        // ---- f layer 0: acc = Cf0 + inject MFMA ----
        {
            const float* cf = &rawCfP[pb];
            #pragma unroll
            for (int r = 0; r < 16; ++r) acc[r] = cf[r];
            half8 ia = *(const half8*)ip; ip += injstep;
            acc = MFMA(ia, xtB, acc);
        }
        // ---- f layers 1..5 ----
        // Region layout (R4): [sinsplit(l-1) | cf(l)+ia(l) loads | injMFMA(l)]
        // <fence> [ah(l) loads | whMFMA(l)x2 | ...next iter's sinsplit...]
        // sinsplit overlaps the independent inject path; fence bounds hoisting
        // to <=7 b128 per region (R1 spill guard).
        for (int l = 1; l < NB; ++l) {
            sinsplit(acc, hB1, hB2);
            const float* cf = &rawCfP[l * 32 + pb];
            floatx16 nacc;
            #pragma unroll
            for (int r = 0; r < 16; ++r) nacc[r] = cf[r];
            half8 ia = *(const half8*)ip; ip += injstep;
            nacc = MFMA(ia, xtB, nacc);
            __builtin_amdgcn_sched_barrier(0);
            const unsigned short* base = &sImg[((l - 1) * 2) * 512 + lane * 8];
            half8 ah0 = *(const half8*)(base);
            half8 ah1 = *(const half8*)(base + 512);
            nacc = MFMA(ah0, hB1, nacc);
            acc  = MFMA(ah1, hB2, nacc);
        }
        // f layer 5's activations (feed g-phase)
        sinsplit(acc, hB1, hB2);

        // ---- g layer 0: gh0 folded into Cg -> only Wz MFMAs (use hB) ----
        half8 gB1, gB2;
        {
            const float* cg = &sCgp[pb];
            #pragma unroll
            for (int r = 0; r < 16; ++r) acc[r] = cg[r];
            const unsigned short* bz = &sImg[10240 + lane * 8];
            half8 wz0 = *(const half8*)(bz);
            half8 wz1 = *(const half8*)(bz + 512);
            acc = MFMA(wz0, hB1, acc);
            acc = MFMA(wz1, hB2, acc);
        }
        // ---- g layers 1..5 ----
        // Region layout (R4): wz-MFMAs (need only hB) moved BEFORE wh-MFMAs
        // (need fresh gB), so sinsplit_g(l-1) overlaps [cg(l)+wz(l) loads |
        // wzMFMA(l)x2]. Fence between wz and wh groups bounds hoisting at
        // <=8 b128 per region. FP sum order within a layer changes
        // (cg+wz+wh vs cg+wh+wz) — ulp-level only.
        for (int l = 1; l < NB; ++l) {
            sinsplit(acc, gB1, gB2);
            const float* cg = &sCgp[l * 32 + pb];
            floatx16 nacc;
            #pragma unroll
            for (int r = 0; r < 16; ++r) nacc[r] = cg[r];
            {
                const unsigned short* bz = &sImg[10240 + (l * 2) * 512 + lane * 8];
                half8 wz0 = *(const half8*)(bz);
                half8 wz1 = *(const half8*)(bz + 512);
                nacc = MFMA(wz0, hB1, nacc);
                nacc = MFMA(wz1, hB2, nacc);
            }
            __builtin_amdgcn_sched_barrier(0);
            {
                const unsigned short* bh = &sImg[5120 + ((l - 1) * 2) * 512 + lane * 8];
                half8 wh0 = *(const half8*)(bh);
                half8 wh1 = *(const half8*)(bh + 512);
                nacc = MFMA(wh0, gB1, nacc);
                acc  = MFMA(wh1, gB2, nacc);
            }
        }

        // ---- decode ----
        float u = 0.0f;
        #pragma unroll
        for (int r = 0; r < 16; ++r) u = fmaf(__builtin_amdgcn_sinf(acc[r]), sdWp[pb + r], u);
        u += __shfl_xor(u, 32);
        if (hk == 0) out[(b * 256 + i) * 256 + j] = u + db;
    }
}

extern "C" void kernel_launch(void* const* d_in, const int* in_sizes, int n_in,
                              void* d_out, int out_size, void* d_ws, size_t ws_size,
                              hipStream_t stream) {
    const float* coords   = (const float*)d_in[0];
    const float* x_params = (const float*)d_in[1];
    const float* t_params = (const float*)d_in[2];
    const float* xW1 = (const float*)d_in[3];
    const float* xb1 = (const float*)d_in[4];
    const float* xW2 = (const float*)d_in[5];
    const float* xb2 = (const float*)d_in[6];
    const float* tW1 = (const float*)d_in[7];
    const float* tb1 = (const float*)d_in[8];
    const float* tW2 = (const float*)d_in[9];
    const float* tb2 = (const float*)d_in[10];
    const float* h0  = (const float*)d_in[11];
    const float* gh0 = (const float*)d_in[12];
    const float* f_Wh = (const float*)d_in[13];
    const float* f_bh = (const float*)d_in[14];
    const float* f_Wz = (const float*)d_in[15];
    const float* f_bz = (const float*)d_in[16];
    const float* g_Wh = (const float*)d_in[17];
    const float* g_bh = (const float*)d_in[18];
    const float* g_Wz = (const float*)d_in[19];
    const float* g_bz = (const float*)d_in[20];
    const float* d_W  = (const float*)d_in[21];
    const float* d_b  = (const float*)d_in[22];

    hipFuncSetAttribute((const void*)sep_mfma,
                        hipFuncAttributeMaxDynamicSharedMemorySize, LDS_BYTES);

    // 16 batches * 32 i-groups * 2 j-halves = 1024 blocks of 512 threads
    // -> exactly 4 blocks/CU, fully co-resident
    sep_mfma<<<1024, 512, LDS_BYTES, stream>>>(
        coords, x_params, t_params, xW1, xb1, xW2, xb2, tW1, tb1, tW2, tb2,
        h0, gh0, f_Wh, f_bh, f_Wz, f_bz, g_Wh, g_bh, g_Wz, g_bz, d_W, d_b,
        (float*)d_out);
}

// Round 6
// 149.436 us; speedup vs baseline: 1.0751x; 1.0751x over previous
//
#include <hip/hip_runtime.h>

#define DIM 32
#define NB  6
#define INV2PI 0.15915494309189535f

typedef __attribute__((ext_vector_type(8)))  _Float16 half8;
typedef __attribute__((ext_vector_type(16))) float floatx16;

union H8I4 { half8 h; int i[4]; };

// RNE f32x2 -> packed f16x2 (prologue only, cost irrelevant)
__device__ __forceinline__ int pkrne(float a, float b) {
    _Float16 h0 = (_Float16)a, h1 = (_Float16)b;
    unsigned short u0, u1;
    __builtin_memcpy(&u0, &h0, 2); __builtin_memcpy(&u1, &h1, 2);
    return (int)(u0 | ((unsigned)u1 << 16));
}
// RTZ f32x2 -> packed f16x2, single v_cvt_pkrtz_f16_f32 (hot path)
#if __has_builtin(__builtin_amdgcn_cvt_pkrtz)
__device__ __forceinline__ int pkrtz(float a, float b) {
    auto h = __builtin_amdgcn_cvt_pkrtz(a, b);
    int r; __builtin_memcpy(&r, &h, 4); return r;
}
#else
#define pkrtz pkrne
#endif

// B-frag slot (s,h,j) holds raw channel P; C/D reg (r,h) holds raw channel Q.
__device__ __forceinline__ int Pmap(int s, int h, int j) { return 16*s + 8*(j>>2) + 4*h + (j&3); }
__device__ __forceinline__ int Qmap(int p)               { int r = p & 15, h = p >> 4; return 8*(r>>2) + 4*h + (r&3); }

#define MFMA(a, b, c) __builtin_amdgcn_mfma_f32_32x32x16_f16((a), (b), (c), 0, 0, 0)

// acc in revolution domain (weights prescaled by 1/2pi): raw v_sin, then
// single-f16 activation pack via v_cvt_pkrtz (R2: measured 87us, absmax 9.8e-4).
__device__ __forceinline__ void sinsplit(const floatx16& acc, half8& b1, half8& b2) {
    H8I4 n1, n2;
    #pragma unroll
    for (int q = 0; q < 4; ++q) {
        n1.i[q] = pkrtz(__builtin_amdgcn_sinf(acc[2*q]),
                        __builtin_amdgcn_sinf(acc[2*q+1]));
        n2.i[q] = pkrtz(__builtin_amdgcn_sinf(acc[8+2*q]),
                        __builtin_amdgcn_sinf(acc[8+2*q+1]));
    }
    b1 = n1.h; b2 = n2.h;
}

// LDS: 160 floats (640 B) + (16384+1536+1536+256) shorts (39424 B) = 40064 B
// -> 4 blocks/CU (160,256 <= 163,840).
#define LDS_BYTES 40064

// NOTE (measured prev session): __launch_bounds__ arg2 = min BLOCKS/CU on
// this toolchain. (512,4) -> 64-VGPR cap.
// Spill tripwire: hbm_bytes (clean ~5 MB; spilled R1 was 2.3 GB at VGPR=64).
// R1 lesson: sched_barrier(0) per layer is a LOAD-HOISTING FENCE — without
// it the unrolled loops hoist ds_reads en masse past the 64-VGPR cap ->
// scratch spill -> 7x regression. DO NOT REMOVE.
// R4 lesson (measured, -7%): fences must sit so that LOADS ARE AT REGION TOP.
// Putting a fence between a layer's MFMAs and its loads delays load issue
// and loses more than the VALU overlap gains. Fence at layer START only.
// R5: Cf/Cg folded into inject-MFMA k-channels 6,7 (B side carries 1.0) ->
// all f32 C-vector LDS reads (48 b128/tile of 86) eliminated; layers start
// from in-place zeroed acc. LDS-bound theory per R2/R3 time-vs-read ratio.
// R5 bench: infra failure ("container failed twice") — resubmitted unchanged.
__global__ __launch_bounds__(512, 4) void sep_mfma(
    const float* __restrict__ coords,
    const float* __restrict__ x_params,
    const float* __restrict__ t_params,
    const float* __restrict__ xW1, const float* __restrict__ xb1,
    const float* __restrict__ xW2, const float* __restrict__ xb2,
    const float* __restrict__ tW1, const float* __restrict__ tb1,
    const float* __restrict__ tW2, const float* __restrict__ tb2,
    const float* __restrict__ h0,  const float* __restrict__ gh0,
    const float* __restrict__ f_Wh, const float* __restrict__ f_bh,
    const float* __restrict__ f_Wz, const float* __restrict__ f_bz,
    const float* __restrict__ g_Wh, const float* __restrict__ g_bh,
    const float* __restrict__ g_Wz, const float* __restrict__ g_bz,
    const float* __restrict__ d_W,  const float* __restrict__ d_b,
    float* __restrict__ out)
{
    extern __shared__ char smem[];
    float* sdWp   = (float*)smem;            // [32] d_W (permuted via Qmap, NOT scaled)
    float* shx    = sdWp + 32;
    float* sht    = shx + 32;
    float* sex    = sht + 32;
    float* set_   = sex + 32;
    // image: [f_Wh l=1..5 | g_Wh l=1..5 | g_Wz l=0..5] x [2 s-halves x 512], f16
    unsigned short* sImg  = (unsigned short*)(set_ + 32);  // 16 slots * 1024 shorts
    // f-inject A-frags: per f-layer 32 rows x 8 f16
    // [z0h,z0h,z0l,z1h,z1h,z1l,CfH,CfL] (hi/lo split, prescaled by 1/2pi)
    unsigned short* sInj  = sImg + 16384;                  // 6 * 256 shorts
    // g-inject A-frags: [0,0,0,0,0,0,CgH,CgL]
    unsigned short* sGnj  = sInj + 1536;                   // 6 * 256 shorts
    unsigned short* sZero = sGnj + 1536;                   // 256 shorts of zeros (hg=1 A half)

    const int tid = threadIdx.x;
    const int b   = blockIdx.x >> 6;          // 64 blocks per batch
    const int ig  = (blockIdx.x >> 1) & 31;   // i-group: 8 i's per block
    const int jg  = blockIdx.x & 1;           // j-half: 4 tiles per block

    // ================= PROLOGUE =================
    // P1: encoder stage 1 + weight A-frag image build (RNE f16, prescaled,
    // packed 2 channels per int store; l=0 of f_Wh/g_Wh folded -> omitted)
    if (tid < 32) {
        float a = xb1[tid];
        for (int k = 0; k < 16; ++k) a = fmaf(x_params[b * 16 + k], xW1[k * 32 + tid], a);
        shx[tid] = __sinf(a);
    } else if (tid < 64) {
        int d = tid - 32;
        float a = tb1[d];
        for (int k = 0; k < 8; ++k) a = fmaf(t_params[b * 8 + k], tW1[k * 32 + d], a);
        sht[d] = __sinf(a);
    }
    if (tid < 128) ((int*)sZero)[tid] = 0;
    {
        int* sImgI = (int*)sImg;
        for (int ii = tid; ii < 8192; ii += 512) {
            int region = ii >> 9;             // slot index 0..15 (block-uniform)
            int r = ii & 511;
            int s = r >> 8, t = r & 255;
            int lane = t >> 2, jj2 = t & 3;
            int m = lane & 31, hg = lane >> 5;
            int c0 = 16*s + 8*(jj2 >> 1) + 4*hg + 2*(jj2 & 1);  // Pmap(s,hg,2*jj2)
            float w0, w1;
            if (region < 5)       { int l = region + 1;  w0 = f_Wh[(l*32 + c0)*32 + m]; w1 = f_Wh[(l*32 + c0 + 1)*32 + m]; }
            else if (region < 10) { int l = region - 4;  w0 = g_Wh[(l*32 + c0)*32 + m]; w1 = g_Wh[(l*32 + c0 + 1)*32 + m]; }
            else                  { int l = region - 10; w0 = g_Wz[(l*64 + c0)*32 + m]; w1 = g_Wz[(l*64 + c0 + 1)*32 + m]; }
            sImgI[ii] = pkrne(w0 * INV2PI, w1 * INV2PI);
        }
    }
    __syncthreads();

    // P2: encoder stage 2 + inject z0/z1 channels + g-inject zero channels + dWp
    if (tid < 32) {
        float a = xb2[tid];
        for (int c = 0; c < 32; ++c) a = fmaf(shx[c], xW2[c * 32 + tid], a);
        sex[tid] = a;
    } else if (tid < 64) {
        int d = tid - 32;
        float a = tb2[d];
        for (int c = 0; c < 32; ++c) a = fmaf(sht[c], tW2[c * 32 + d], a);
        set_[d] = a;
    }
    if (tid < 192) {
        // f-inject frag for layer l, output row m (RAW row: A-side mapping)
        int l = tid >> 5, m = tid & 31;
        float z0 = f_Wz[(l * 34 + 0) * 32 + m] * INV2PI;
        float z1 = f_Wz[(l * 34 + 1) * 32 + m] * INV2PI;
        _Float16 h0_ = (_Float16)z0; float z0h = (float)h0_, z0l = z0 - z0h;
        _Float16 h1_ = (_Float16)z1; float z1h = (float)h1_, z1l = z1 - z1h;
        int* p = (int*)sInj + 4 * tid;
        p[0] = pkrne(z0h, z0h);
        p[1] = pkrne(z0l, z1h);
        p[2] = pkrne(z1h, z1l);
        int* q = (int*)sGnj + 4 * tid;
        q[0] = 0; q[1] = 0; q[2] = 0;
    }
    if (tid < 32) sdWp[tid] = d_W[Qmap(tid)];
    __syncthreads();

    // P3: Cf and Cg (RAW row m — they enter through the A-matrix now, so no
    // Qmap permutation; prescaled; h0/gh0 matvecs folded into l=0).
    // Stored as hi/lo f16 pair in inject channels 6,7 -> ~2^-22 rel error.
    if (tid < 192) {
        int l = tid >> 5, m = tid & 31;
        float a = f_bh[l * 32 + m] + f_bz[l * 32 + m];
        for (int c = 0; c < 32; ++c) a = fmaf(set_[c], f_Wz[(l * 34 + 2 + c) * 32 + m], a);
        if (l == 0)
            for (int c = 0; c < 32; ++c) a = fmaf(h0[c], f_Wh[c * 32 + m], a);
        a *= INV2PI;
        _Float16 aH_ = (_Float16)a; float aH = (float)aH_, aL = a - aH;
        ((int*)sInj)[4 * tid + 3] = pkrne(aH, aL);
        float g = g_bh[l * 32 + m] + g_bz[l * 32 + m];
        for (int c = 0; c < 32; ++c) g = fmaf(sex[c], g_Wz[(l * 64 + 32 + c) * 32 + m], g);
        if (l == 0)
            for (int c = 0; c < 32; ++c) g = fmaf(gh0[c], g_Wh[c * 32 + m], g);
        g *= INV2PI;
        _Float16 gH_ = (_Float16)g; float gH = (float)gH_, gL = g - gH;
        ((int*)sGnj)[4 * tid + 3] = pkrne(gH, gL);
    }
    __syncthreads();

    // ================= MAIN =================
    const int lane = tid & 63, wave = tid >> 6;
    const int i = ig * 8 + wave;
    const int e = lane & 31, hk = lane >> 5;
    const int pb = hk * 16;
    const float ti = coords[(b * 256 + i) * 2 + 1];
    const float db = d_b[0];

    // hi/lo split of ti (wave-uniform), hoisted out of the tile loop
    float th_, tl_;
    { _Float16 h = (_Float16)ti; th_ = (float)h; tl_ = ti - th_; }

    // inject A-frag bases: hg=0 lanes walk per layer; hg=1 lanes read the
    // shared zero block (their k-channels 8..15 are unused -> A rows exact 0,
    // which also makes hk=1 lanes' B content don't-care).
    const unsigned short* injbase = hk ? sZero : (sInj + e * 8);
    const unsigned short* gnjbase = hk ? sZero : (sGnj + e * 8);
    const int injstep = hk ? 0 : 256;   // shorts per layer

    #pragma unroll 1
    for (int t = 0; t < 4; ++t) {
        const int tile = jg * 4 + t;
        const int j = tile * 32 + e;
        const float xj = coords[(b * 256 + j) * 2];

        // B-frag [xh,xl,xh,th,tl,th,1,1]: compensated hi/lo split; channels
        // 6,7 = 1.0 (exact in f16) pick up the Cf/Cg fold from the A-side.
        float xh_, xl_;
        { _Float16 h = (_Float16)xj; xh_ = (float)h; xl_ = xj - xh_; }
        H8I4 xtb;
        xtb.i[0] = pkrtz(xh_, xl_);
        xtb.i[1] = pkrtz(xh_, th_);
        xtb.i[2] = pkrtz(tl_, th_);
        xtb.i[3] = 0x3C003C00;   // (1.0h, 1.0h)
        const half8 xtB = xtb.h;

        floatx16 acc;
        half8 hB1, hB2;
        const unsigned short* ip = injbase;
        const unsigned short* gp = gnjbase;

        // ---- f layer 0: acc = inject(z0*x + z1*t + Cf0) from zero ----
        {
            half8 ia = *(const half8*)ip; ip += injstep;
            floatx16 z;
            #pragma unroll
            for (int r = 0; r < 16; ++r) z[r] = 0.0f;
            acc = MFMA(ia, xtB, z);
            sinsplit(acc, hB1, hB2);
        }
        // ---- f layers 1..5: zero -> 2 Wh MFMAs -> inject(+Cf) last ----
        // Region = [fence | 3 loads at top | compute]. Layer head has NO lgkm
        // dependency (zero-init + reg-resident hB) — ah latency is covered by
        // the zero-init and the previous sinsplit tail.
        for (int l = 1; l < NB; ++l) {
            __builtin_amdgcn_sched_barrier(0);
            const unsigned short* base = &sImg[((l - 1) * 2) * 512 + lane * 8];
            half8 ah0 = *(const half8*)(base);
            half8 ah1 = *(const half8*)(base + 512);
            half8 ia  = *(const half8*)ip; ip += injstep;
            floatx16 z;
            #pragma unroll
            for (int r = 0; r < 16; ++r) z[r] = 0.0f;
            z = MFMA(ah0, hB1, z);
            z = MFMA(ah1, hB2, z);
            acc = MFMA(ia, xtB, z);
            sinsplit(acc, hB1, hB2);
        }

        // ---- g layer 0: zero -> Wz MFMAs -> g-inject(+Cg0, gh0 folded) ----
        half8 gB1, gB2;
        {
            __builtin_amdgcn_sched_barrier(0);
            const unsigned short* bz = &sImg[10240 + lane * 8];
            half8 wz0 = *(const half8*)(bz);
            half8 wz1 = *(const half8*)(bz + 512);
            half8 gi  = *(const half8*)gp; gp += injstep;
            floatx16 z;
            #pragma unroll
            for (int r = 0; r < 16; ++r) z[r] = 0.0f;
            z = MFMA(wz0, hB1, z);
            z = MFMA(wz1, hB2, z);
            acc = MFMA(gi, xtB, z);
            sinsplit(acc, gB1, gB2);
        }
        // ---- g layers 1..5: zero -> Wz (hB, ready) -> Wh (fresh gB) ->
        //      g-inject(+Cg) last. FP order change vs R3 is ulp-level. ----
        for (int l = 1; l < NB; ++l) {
            __builtin_amdgcn_sched_barrier(0);
            const unsigned short* bz = &sImg[10240 + (l * 2) * 512 + lane * 8];
            const unsigned short* bh = &sImg[5120 + ((l - 1) * 2) * 512 + lane * 8];
            half8 wz0 = *(const half8*)(bz);
            half8 wz1 = *(const half8*)(bz + 512);
            half8 wh0 = *(const half8*)(bh);
            half8 wh1 = *(const half8*)(bh + 512);
            half8 gi  = *(const half8*)gp; gp += injstep;
            floatx16 z;
            #pragma unroll
            for (int r = 0; r < 16; ++r) z[r] = 0.0f;
            z = MFMA(wz0, hB1, z);
            z = MFMA(wz1, hB2, z);
            z = MFMA(wh0, gB1, z);
            z = MFMA(wh1, gB2, z);
            acc = MFMA(gi, xtB, z);
            if (l < NB - 1) sinsplit(acc, gB1, gB2);
        }

        // ---- decode ----
        float u = 0.0f;
        #pragma unroll
        for (int r = 0; r < 16; ++r) u = fmaf(__builtin_amdgcn_sinf(acc[r]), sdWp[pb + r], u);
        u += __shfl_xor(u, 32);
        if (hk == 0) out[(b * 256 + i) * 256 + j] = u + db;
    }
}

extern "C" void kernel_launch(void* const* d_in, const int* in_sizes, int n_in,
                              void* d_out, int out_size, void* d_ws, size_t ws_size,
                              hipStream_t stream) {
    const float* coords   = (const float*)d_in[0];
    const float* x_params = (const float*)d_in[1];
    const float* t_params = (const float*)d_in[2];
    const float* xW1 = (const float*)d_in[3];
    const float* xb1 = (const float*)d_in[4];
    const float* xW2 = (const float*)d_in[5];
    const float* xb2 = (const float*)d_in[6];
    const float* tW1 = (const float*)d_in[7];
    const float* tb1 = (const float*)d_in[8];
    const float* tW2 = (const float*)d_in[9];
    const float* tb2 = (const float*)d_in[10];
    const float* h0  = (const float*)d_in[11];
    const float* gh0 = (const float*)d_in[12];
    const float* f_Wh = (const float*)d_in[13];
    const float* f_bh = (const float*)d_in[14];
    const float* f_Wz = (const float*)d_in[15];
    const float* f_bz = (const float*)d_in[16];
    const float* g_Wh = (const float*)d_in[17];
    const float* g_bh = (const float*)d_in[18];
    const float* g_Wz = (const float*)d_in[19];
    const float* g_bz = (const float*)d_in[20];
    const float* d_W  = (const float*)d_in[21];
    const float* d_b  = (const float*)d_in[22];

    hipFuncSetAttribute((const void*)sep_mfma,
                        hipFuncAttributeMaxDynamicSharedMemorySize, LDS_BYTES);

    // 16 batches * 32 i-groups * 2 j-halves = 1024 blocks of 512 threads
    // -> exactly 4 blocks/CU, fully co-resident
    sep_mfma<<<1024, 512, LDS_BYTES, stream>>>(
        coords, x_params, t_params, xW1, xb1, xW2, xb2, tW1, tb1, tW2, tb2,
        h0, gh0, f_Wh, f_bh, f_Wz, f_bz, g_Wh, g_bh, g_Wz, g_bz, d_W, d_b,
        (float*)d_out);
}